// Round 15
// baseline (573.646 us; speedup 1.0000x reference)
//
#include <hip/hip_runtime.h>
#include <stdint.h>
#include <stdio.h>

#define T_TOK 4096
#define DMODEL 2048
#define NEXP 8
#define DFF 1408
#define DFFS 2816
#define NSLOT 8192   // T_TOK * 2

// schedule-table grid bounds (worst case): routed m-blocks sum <= 39
#define GU_GRID (16 * 22 + 39 * 11)   // 781
#define DN_GRID (16 * 8 + 39 * 8)     // 440
#define RTOK 8                        // tokens per router block
#define RBLK (T_TOK / RTOK)           // 512 router blocks
#define CONV_ALL 1536                 // all-weight convert blocks appended to router

typedef unsigned short u16;
typedef short s16x8 __attribute__((ext_vector_type(8)));
typedef unsigned short u16x4 __attribute__((ext_vector_type(4)));
typedef __bf16 bf16x8 __attribute__((ext_vector_type(8)));
typedef float f32x4 __attribute__((ext_vector_type(4)));

__device__ __forceinline__ u16 f2bf(float f) {
  uint32_t u = __builtin_bit_cast(uint32_t, f);
  u += 0x7fffu + ((u >> 16) & 1u);
  return (u16)(u >> 16);
}
__device__ __forceinline__ float bf2f(u16 h) {
  uint32_t u = ((uint32_t)h) << 16;
  return __builtin_bit_cast(float, u);
}

// async global->LDS, 16B per lane; LDS dest = wave-uniform base + lane*16
__device__ __forceinline__ void gl16(const u16* g, u16* l) {
  __builtin_amdgcn_global_load_lds((const __attribute__((address_space(1))) void*)g,
                                   (__attribute__((address_space(3))) void*)l,
                                   16, 0, 0);
}

#define BARRIER() asm volatile("s_barrier" ::: "memory")
#define SBAR()    __builtin_amdgcn_sched_barrier(0)

__device__ __forceinline__ void conv8(const float* __restrict__ s, u16* __restrict__ d,
                                      long k) {
  float4 a = ((const float4*)s)[2 * k];
  float4 b = ((const float4*)s)[2 * k + 1];
  s16x8 r;
  r[0] = (short)f2bf(a.x); r[1] = (short)f2bf(a.y);
  r[2] = (short)f2bf(a.z); r[3] = (short)f2bf(a.w);
  r[4] = (short)f2bf(b.x); r[5] = (short)f2bf(b.y);
  r[6] = (short)f2bf(b.z); r[7] = (short)f2bf(b.w);
  ((s16x8*)d)[k] = r;
}

__global__ void k_zero(int* __restrict__ counts) {
  if (threadIdx.x < NEXP) counts[threadIdx.x] = 0;
}

// ---------------- router v3: 8 tokens/block, gw-in-registers + convert backfill ----
// Blocks [0, RBLK): router, 8 tokens each. Each wave owns 2 experts; per k-step it
// loads g0,g1 ONCE and reuses across 8 tokens (gw traffic 268MB -> 33MB; 8 indep
// f64 chains per wave for ILP). Per-token f64 summation chain, shuffle order, top-2,
// weight math and atomics are BITWISE IDENTICAL to the passing router (lanes 0..7
// each finalize one token with the same per-token code).
// Blocks [RBLK, RBLK+CONV_ALL): grid-stride fp32->bf16 convert of all 6 weights
// (kernel has ~no LDS -> convert blocks co-reside; r13 lesson).
__global__ void k_router(const float* __restrict__ x, const float* __restrict__ gw,
                         u16* __restrict__ xb,
                         float* __restrict__ tkw, int* __restrict__ tki,
                         int* __restrict__ counts,
                         const float* __restrict__ wgF, u16* __restrict__ wbg,
                         const float* __restrict__ wuF, u16* __restrict__ wbu,
                         const float* __restrict__ wsgF, u16* __restrict__ wbsg,
                         const float* __restrict__ wsuF, u16* __restrict__ wbsu,
                         const float* __restrict__ wdF, u16* __restrict__ wbd,
                         const float* __restrict__ wsdF, u16* __restrict__ wbsd) {
  if (blockIdx.x >= RBLK) {   // ---- convert path ----
    const long N1 = (long)NEXP * DFF * DMODEL / 8;   // 2883584 (also wd size)
    const long NS = (long)DFFS * DMODEL / 8;         // 720896  (also wsd size)
    const long total = 3 * N1 + 3 * NS;
    const long stride = (long)CONV_ALL * 256;
    for (long i = (long)(blockIdx.x - RBLK) * 256 + threadIdx.x; i < total; i += stride) {
      long k = i;
      if (k < N1)            conv8(wgF, wbg, k);
      else { k -= N1;
        if (k < N1)          conv8(wuF, wbu, k);
        else { k -= N1;
          if (k < NS)        conv8(wsgF, wbsg, k);
          else { k -= NS;
            if (k < NS)      conv8(wsuF, wbsu, k);
            else { k -= NS;
              if (k < N1)    conv8(wdF, wbd, k);
              else           conv8(wsdF, wbsd, k - N1);
            }
          }
        }
      }
    }
    return;
  }
  __shared__ double sm[RTOK][NEXP];
  const int t0 = blockIdx.x * RTOK;
  int tid = threadIdx.x;
  int lane = tid & 63, wv = tid >> 6;     // 4 waves
  const float4* gr = (const float4*)gw;
  int e0 = wv * 2, e1 = e0 + 1;
  double a0[RTOK], a1[RTOK];
#pragma unroll
  for (int tok = 0; tok < RTOK; ++tok) { a0[tok] = 0.0; a1[tok] = 0.0; }
#pragma unroll
  for (int it = 0; it < DMODEL / 4 / 64; ++it) {   // 8 k-steps
    int idx = it * 64 + lane;
    float4 g0 = gr[e0 * (DMODEL / 4) + idx];
    float4 g1 = gr[e1 * (DMODEL / 4) + idx];
#pragma unroll
    for (int tok = 0; tok < RTOK; ++tok) {
      float4 xv = ((const float4*)(x + (size_t)(t0 + tok) * DMODEL))[idx];
      a0[tok] += (double)xv.x * g0.x + (double)xv.y * g0.y +
                 (double)xv.z * g0.z + (double)xv.w * g0.w;
      a1[tok] += (double)xv.x * g1.x + (double)xv.y * g1.y +
                 (double)xv.z * g1.z + (double)xv.w * g1.w;
      if (wv == 0) {   // fused x -> bf16 (wave 0 only; same values as before)
        u16x4 r = { f2bf(xv.x), f2bf(xv.y), f2bf(xv.z), f2bf(xv.w) };
        ((u16x4*)(xb + (size_t)(t0 + tok) * DMODEL))[idx] = r;
      }
    }
  }
#pragma unroll
  for (int tok = 0; tok < RTOK; ++tok) {
#pragma unroll
    for (int off = 32; off; off >>= 1) {
      a0[tok] += __shfl_down(a0[tok], off, 64);
      a1[tok] += __shfl_down(a1[tok], off, 64);
    }
  }
  if (lane == 0) {
#pragma unroll
    for (int tok = 0; tok < RTOK; ++tok) { sm[tok][e0] = a0[tok]; sm[tok][e1] = a1[tok]; }
  }
  __syncthreads();
  if (tid < RTOK) {
    int t = t0 + tid;
    double acc[NEXP];
#pragma unroll
    for (int e = 0; e < NEXP; ++e) acc[e] = sm[tid][e];
    int i0 = 0; double v0 = acc[0];
    for (int e = 1; e < NEXP; ++e) if (acc[e] > v0) { v0 = acc[e]; i0 = e; }
    int i1 = -1; double v1 = -1e300;
    for (int e = 0; e < NEXP; ++e) if (e != i0 && acc[e] > v1) { v1 = acc[e]; i1 = e; }
    double r = exp(v1 - v0);
    float w0 = (float)(1.0 / (1.0 + r));
    float w1 = 1.0f - w0;
    tkw[2 * t] = w0; tkw[2 * t + 1] = w1;
    tki[2 * t] = i0; tki[2 * t + 1] = i1;
    atomicAdd(&counts[i0], 1);
    atomicAdd(&counts[i1], 1);
  }
}

// ---------------- merged scan + schedule-table builder (round-9 ordering) ----------------
// desc: bit31 = shared flag, bits24-27 = expert, bits12-23 = mb, bits0-11 = nb.
// GU: nb indexes 128-col panels (g+u fused per block). DN: nb indexes 256-col.
// Shared entries FIRST (LPT for DOWN: shared-down blocks have 2x the K).
__global__ void k_scan_sched(const int* __restrict__ counts, int* __restrict__ offs,
                             int* __restrict__ cursor, int* __restrict__ tblGU,
                             int* __restrict__ tblDN, int* __restrict__ nact) {
  if (threadIdx.x != 0 || blockIdx.x != 0) return;
  int s = 0;
  for (int e = 0; e < NEXP; ++e) { offs[e] = s; cursor[e] = s; s += counts[e]; }
  offs[NEXP] = s;
  int g = 0, d = 0;
  for (int m = 0; m < T_TOK / 256; ++m) {
    for (int nb = 0; nb < DFFS / 128; ++nb)
      tblGU[g++] = (int)(0x80000000u | (m << 12) | nb);
    for (int nb = 0; nb < DMODEL / 256; ++nb)
      tblDN[d++] = (int)(0x80000000u | (m << 12) | nb);
  }
  for (int e = 0; e < NEXP; ++e) {
    int mb = (counts[e] + 255) >> 8;
    for (int m = 0; m < mb; ++m) {
      for (int nb = 0; nb < DFF / 128; ++nb)
        tblGU[g++] = (e << 24) | (m << 12) | nb;
      for (int nb = 0; nb < DMODEL / 256; ++nb)
        tblDN[d++] = (e << 24) | (m << 12) | nb;
    }
  }
  nact[0] = g; nact[1] = d;
}

__global__ void k_assign(const int* __restrict__ tki, int* __restrict__ cursor,
                         int* __restrict__ pos, int* __restrict__ slot_tok) {
  int t = blockIdx.x * 256 + threadIdx.x;
  if (t >= T_TOK) return;
#pragma unroll
  for (int k = 0; k < 2; ++k) {
    int e = tki[2 * t + k];
    int p = atomicAdd(&cursor[e], 1);
    pos[2 * t + k] = p;
    slot_tok[p] = t;
  }
}

// ---------------- 256-row NT bf16 GEMM, reads-lead pipeline (round-9), fused-silu GU --
// PHASE 0 = gate/up+silu fused: 256m x 128 cols, B-tile rows interleaved;
//   epilogue computes h = silu(g)*u in-register, writes h only.
// PHASE 1 = merged down (runtime K = 1408/2816), 256x256, writes yr / out.
// 512 thr = 8 waves (2M x 4N), BK=64, LDS 2 x 64KB dbuf, T2 XOR-swizzle.
template <int PHASE>
__launch_bounds__(512, 2)
__global__ void k_gemm8(const int* __restrict__ tbl, const int* __restrict__ nact,
                        const u16* __restrict__ xb,
                        const u16* __restrict__ hr, const u16* __restrict__ hs,
                        const u16* __restrict__ wbg, const u16* __restrict__ wbu,
                        const u16* __restrict__ wbd,
                        const u16* __restrict__ wbsg, const u16* __restrict__ wbsu,
                        const u16* __restrict__ wbsd,
                        u16* __restrict__ P1r, u16* __restrict__ P1s,
                        u16* __restrict__ yr, float* __restrict__ out,
                        const int* __restrict__ offs, const int* __restrict__ counts,
                        const int* __restrict__ slot_tok) {
  __shared__ __attribute__((aligned(16))) u16 lds[2 * 32768];  // 128 KiB

  if ((int)blockIdx.x >= nact[PHASE]) return;
  const int desc = tbl[blockIdx.x];
  const bool shrd = desc < 0;
  const int e = (desc >> 24) & 0xF;
  const int m0 = ((desc >> 12) & 0xFFF) * 256;
  const int n0 = (desc & 0xFFF) * (PHASE == 0 ? 128 : 256);

  const u16 *A, *Bg, *Bu;
  u16* C1;
  float* OF = nullptr;
  int base, cnt, HS, K;
  bool gather = false;
  if constexpr (PHASE == 0) {
    K = DMODEL;
    if (shrd) {
      A = xb; base = 0; cnt = T_TOK;
      Bg = wbsg; Bu = wbsu; C1 = P1s; HS = DFFS;
    } else {
      A = xb; gather = true; base = offs[e]; cnt = counts[e];
      size_t es = (size_t)e * DFF * DMODEL;
      Bg = wbg + es; Bu = wbu + es; C1 = P1r; HS = DFF;
    }
  } else {
    HS = DMODEL;
    if (shrd) {
      A = hs; base = 0; cnt = T_TOK; K = DFFS;
      Bg = Bu = wbsd; OF = out; C1 = nullptr;
    } else {
      A = hr; base = offs[e]; cnt = counts[e]; K = DFF;
      Bg = Bu = wbd + (size_t)e * DMODEL * DFF; C1 = yr;
    }
  }
  const int NT = K >> 6;

  int tid = threadIdx.x;
  int lane = tid & 63, wv = tid >> 6;
  int wm = wv >> 2, wn = wv & 3;
  int fr = lane & 15, fq = lane >> 4;

  // --- staging source pointers: 4 A-slabs + 4 B-slabs (64 rows each)
  int srow = tid >> 3;                     // wv*8 + (lane>>3), 0..63
  int sslot = (tid & 7) ^ (srow & 7);      // T2 pre-swizzle (involution)
  const u16* ap[4]; const u16* bp[4];
#pragma unroll
  for (int h = 0; h < 4; ++h) {
    int r = h * 64 + srow;                 // tile row 0..255
    int ra = m0 + r; ra = ra < cnt ? ra : cnt - 1;
    int ga = gather ? slot_tok[base + ra] : base + ra;
    ap[h] = A + (size_t)ga * K + sslot * 8;
    const u16* bb;
    if constexpr (PHASE == 0) {
      // interleaved g/u B-tile: row r -> wave wn_r = r>>6, s = r&63;
      // s<32: wg col n0+wn_r*32+s ; s>=32: wu col n0+wn_r*32+(s-32)
      int wnr = r >> 6, s = r & 63;
      int col = n0 + wnr * 32 + (s & 31);
      bb = (s < 32 ? Bg : Bu) + (size_t)col * K;
    } else {
      bb = Bg + (size_t)(n0 + r) * K;
    }
    bp[h] = bb + sslot * 8;
  }

#define STG_A(h, bufi, kt) gl16(ap[h] + (size_t)(kt) * 64, \
                                lds + (bufi) * 32768 + (h) * 4096 + wv * 512)
#define STG_B(h, bufi, kt) gl16(bp[h] + (size_t)(kt) * 64, \
                                lds + (bufi) * 32768 + 16384 + (h) * 4096 + wv * 512)

  // --- read bases (u16 units); swizzled k-slot is lane-constant per ks
  int sKs0 = ((0 + fq) ^ (fr & 7)) * 8;
  int sKs1 = ((4 + fq) ^ (fr & 7)) * 8;
  int aBase = wm * 8192 + fr * 64;                                   // + i*1024
  int bBase = 16384 + (wn >> 1) * 8192 + ((wn & 1) * 64 + fr) * 64;  // + j*1024

  f32x4 acc[8][4];
#pragma unroll
  for (int i = 0; i < 8; ++i)
#pragma unroll
    for (int j = 0; j < 4; ++j) acc[i][j] = (f32x4){0.f, 0.f, 0.f, 0.f};

  // prologue: full tile0 + A-slabs of tile1
  STG_A(0, 0, 0); STG_A(1, 0, 0); STG_A(2, 0, 0); STG_A(3, 0, 0);
  STG_B(0, 0, 0); STG_B(1, 0, 0); STG_B(2, 0, 0); STG_B(3, 0, 0);
  if (NT > 1) { STG_A(0, 1, 1); STG_A(1, 1, 1); STG_A(2, 1, 1); STG_A(3, 1, 1); }
  if (NT > 1) asm volatile("s_waitcnt vmcnt(4)" ::: "memory");
  else        asm volatile("s_waitcnt vmcnt(0)" ::: "memory");
  BARRIER();
  SBAR();

  bf16x8 rAa[4][2], rAb[4][2], rB01[2][2], rB23[2][2];
#pragma unroll
  for (int il = 0; il < 4; ++il) {
    rAa[il][0] = *(const bf16x8*)(lds + aBase + il * 1024 + sKs0);
    rAa[il][1] = *(const bf16x8*)(lds + aBase + il * 1024 + sKs1);
  }
#pragma unroll
  for (int jl = 0; jl < 2; ++jl) {
    rB01[jl][0] = *(const bf16x8*)(lds + bBase + jl * 1024 + sKs0);
    rB01[jl][1] = *(const bf16x8*)(lds + bBase + jl * 1024 + sKs1);
  }

  for (int t = 0; t < NT; ++t) {
    const int buf = t & 1, nbuf = buf ^ 1;
    const u16* lbuf = lds + buf * 32768;
    const u16* lbufN = lds + nbuf * 32768;
    const bool hn1 = (t + 1) < NT, hn2 = (t + 2) < NT;

    // ---- s0: read B23(t); stage B0,B1(t+1)->nbuf; MFMA mq0 x nq0
#pragma unroll
    for (int jl = 0; jl < 2; ++jl) {
      rB23[jl][0] = *(const bf16x8*)(lbuf + bBase + (2 + jl) * 1024 + sKs0);
      rB23[jl][1] = *(const bf16x8*)(lbuf + bBase + (2 + jl) * 1024 + sKs1);
    }
    if (hn1) { STG_B(0, nbuf, t + 1); STG_B(1, nbuf, t + 1); }
    __builtin_amdgcn_s_setprio(1);
#pragma unroll
    for (int il = 0; il < 4; ++il)
#pragma unroll
      for (int jl = 0; jl < 2; ++jl) {
        acc[il][jl] = __builtin_amdgcn_mfma_f32_16x16x32_bf16(rAa[il][0], rB01[jl][0], acc[il][jl], 0, 0, 0);
        acc[il][jl] = __builtin_amdgcn_mfma_f32_16x16x32_bf16(rAa[il][1], rB01[jl][1], acc[il][jl], 0, 0, 0);
      }
    __builtin_amdgcn_s_setprio(0);

    // ---- s1: read A13(t); stage B2,B3(t+1)->nbuf; MFMA mq0 x nq1
#pragma unroll
    for (int il = 0; il < 4; ++il) {
      rAb[il][0] = *(const bf16x8*)(lbuf + aBase + (4 + il) * 1024 + sKs0);
      rAb[il][1] = *(const bf16x8*)(lbuf + aBase + (4 + il) * 1024 + sKs1);
    }
    if (hn1) { STG_B(2, nbuf, t + 1); STG_B(3, nbuf, t + 1); }
    __builtin_amdgcn_s_setprio(1);
#pragma unroll
    for (int il = 0; il < 4; ++il)
#pragma unroll
      for (int jl = 0; jl < 2; ++jl) {
        acc[il][2 + jl] = __builtin_amdgcn_mfma_f32_16x16x32_bf16(rAa[il][0], rB23[jl][0], acc[il][2 + jl], 0, 0, 0);
        acc[il][2 + jl] = __builtin_amdgcn_mfma_f32_16x16x32_bf16(rAa[il][1], rB23[jl][1], acc[il][2 + jl], 0, 0, 0);
      }
    __builtin_amdgcn_s_setprio(0);

    // ---- s2: drain reads + barrier (frees buf for t+2 A-stages); MFMA mq1 x nq0
    asm volatile("s_waitcnt lgkmcnt(0)" ::: "memory");
    BARRIER();
    SBAR();
    if (hn2) { STG_A(0, buf, t + 2); STG_A(1, buf, t + 2); }
    __builtin_amdgcn_s_setprio(1);
#pragma unroll
    for (int il = 0; il < 4; ++il)
#pragma unroll
      for (int jl = 0; jl < 2; ++jl) {
        acc[4 + il][jl] = __builtin_amdgcn_mfma_f32_16x16x32_bf16(rAb[il][0], rB01[jl][0], acc[4 + il][jl], 0, 0, 0);
        acc[4 + il][jl] = __builtin_amdgcn_mfma_f32_16x16x32_bf16(rAb[il][1], rB01[jl][1], acc[4 + il][jl], 0, 0, 0);
      }
    __builtin_amdgcn_s_setprio(0);

    // ---- s3: vmcnt+barrier (t+1 fully staged); stage A2,A3(t+2); read A02/B01(t+1); MFMA mq1 x nq1
    if (hn1) {
      if (hn2) asm volatile("s_waitcnt vmcnt(2)" ::: "memory");
      else     asm volatile("s_waitcnt vmcnt(0)" ::: "memory");
      BARRIER();
      SBAR();
      if (hn2) { STG_A(2, buf, t + 2); STG_A(3, buf, t + 2); }
#pragma unroll
      for (int il = 0; il < 4; ++il) {
        rAa[il][0] = *(const bf16x8*)(lbufN + aBase + il * 1024 + sKs0);
        rAa[il][1] = *(const bf16x8*)(lbufN + aBase + il * 1024 + sKs1);
      }
#pragma unroll
      for (int jl = 0; jl < 2; ++jl) {
        rB01[jl][0] = *(const bf16x8*)(lbufN + bBase + jl * 1024 + sKs0);
        rB01[jl][1] = *(const bf16x8*)(lbufN + bBase + jl * 1024 + sKs1);
      }
    }
    __builtin_amdgcn_s_setprio(1);
#pragma unroll
    for (int il = 0; il < 4; ++il)
#pragma unroll
      for (int jl = 0; jl < 2; ++jl) {
        acc[4 + il][2 + jl] = __builtin_amdgcn_mfma_f32_16x16x32_bf16(rAb[il][0], rB23[jl][0], acc[4 + il][2 + jl], 0, 0, 0);
        acc[4 + il][2 + jl] = __builtin_amdgcn_mfma_f32_16x16x32_bf16(rAb[il][1], rB23[jl][1], acc[4 + il][2 + jl], 0, 0, 0);
      }
    __builtin_amdgcn_s_setprio(0);
  }
#undef STG_A
#undef STG_B

  // --- epilogue ---
#pragma unroll
  for (int i = 0; i < 8; ++i) {
    int row_t = wm * 128 + i * 16 + fq * 4;
#pragma unroll
    for (int r = 0; r < 4; ++r) {
      int m = m0 + row_t + r;
      if (m >= cnt) continue;
      size_t rowoff = (size_t)(base + m) * (size_t)HS;
      if constexpr (PHASE == 0) {
        // h = silu(g) * u ; g = acc[i][jl], u = acc[i][2+jl], col = n0+wn*32+jl*16+fr
#pragma unroll
        for (int jl = 0; jl < 2; ++jl) {
          float g = acc[i][jl][r];
          float u = acc[i][2 + jl][r];
          float hval = (g / (1.f + __expf(-g))) * u;
          C1[rowoff + (n0 + wn * 32 + jl * 16 + fr)] = f2bf(hval);
        }
      } else {
#pragma unroll
        for (int j = 0; j < 4; ++j) {
          int col_t = n0 + wn * 64 + j * 16 + fr;
          float v = acc[i][j][r];
          if (shrd) OF[rowoff + col_t] = v;
          else      C1[rowoff + col_t] = f2bf(v);
        }
      }
    }
  }
}

// ---------------- y[t] += w0*yr[pos0] + w1*yr[pos1] ----------------
__global__ void k_combine(float* __restrict__ y, const u16* __restrict__ yr,
                          const float* __restrict__ tkw, const int* __restrict__ pos) {
  int t = blockIdx.x;
  int i = threadIdx.x;
  float w0 = tkw[2 * t], w1 = tkw[2 * t + 1];
  size_t p0 = (size_t)pos[2 * t] * DMODEL, p1 = (size_t)pos[2 * t + 1] * DMODEL;
  int d0 = i * 8;
  s16x8 a = *(const s16x8*)(yr + p0 + d0);
  s16x8 b = *(const s16x8*)(yr + p1 + d0);
  float* yo = y + (size_t)t * DMODEL + d0;
#pragma unroll
  for (int j = 0; j < 8; ++j)
    yo[j] += w0 * bf2f((u16)a[j]) + w1 * bf2f((u16)b[j]);
}

extern "C" void kernel_launch(void* const* d_in, const int* in_sizes, int n_in,
                              void* d_out, int out_size, void* d_ws, size_t ws_size,
                              hipStream_t stream) {
  const float* x   = (const float*)d_in[0];
  const float* gw  = (const float*)d_in[1];
  const float* wg  = (const float*)d_in[2];
  const float* wu  = (const float*)d_in[3];
  const float* wd  = (const float*)d_in[4];
  const float* wsg = (const float*)d_in[5];
  const float* wsu = (const float*)d_in[6];
  const float* wsd = (const float*)d_in[7];
  float* out = (float*)d_out;

  char* ws = (char*)d_ws;
  size_t o = 0;
  auto alloc = [&](size_t bytes) -> void* {
    void* p = ws + o;
    o += (bytes + 255) & ~(size_t)255;
    return p;
  };
  u16* xb   = (u16*)alloc((size_t)T_TOK * DMODEL * 2);
  u16* wbg  = (u16*)alloc((size_t)NEXP * DFF * DMODEL * 2);
  u16* wbu  = (u16*)alloc((size_t)NEXP * DFF * DMODEL * 2);
  u16* wbd  = (u16*)alloc((size_t)NEXP * DMODEL * DFF * 2);
  u16* wbsg = (u16*)alloc((size_t)DFFS * DMODEL * 2);
  u16* wbsu = (u16*)alloc((size_t)DFFS * DMODEL * 2);
  u16* wbsd = (u16*)alloc((size_t)DMODEL * DFFS * 2);
  u16* P1r  = (u16*)alloc((size_t)NSLOT * DFF * 2);    // h_r (silu fused in GU)
  u16* P1s  = (u16*)alloc((size_t)T_TOK * DFFS * 2);   // h_s
  u16* yr   = (u16*)alloc((size_t)NSLOT * DMODEL * 2);
  float* tkw = (float*)alloc((size_t)T_TOK * 2 * 4);
  int* tki   = (int*)alloc((size_t)T_TOK * 2 * 4);
  int* pos   = (int*)alloc((size_t)T_TOK * 2 * 4);
  int* slot_tok = (int*)alloc((size_t)NSLOT * 4);
  int* counts   = (int*)alloc(64);
  int* offs     = (int*)alloc(64);
  int* cursor   = (int*)alloc(64);
  int* tblGU    = (int*)alloc(GU_GRID * 4);
  int* tblDN    = (int*)alloc(DN_GRID * 4);
  int* nact     = (int*)alloc(64);
  if (o > ws_size) {
    fprintf(stderr, "kernel_launch: ws too small: need %zu have %zu\n", o, ws_size);
    return;
  }

  // --- routing (8 tok/block, produces xb; ALL weight converts backfilled) ---
  k_zero<<<1, 64, 0, stream>>>(counts);
  k_router<<<RBLK + CONV_ALL, 256, 0, stream>>>(x, gw, xb, tkw, tki, counts,
                                                wg, wbg, wu, wbu, wsg, wbsg, wsu, wbsu,
                                                wd, wbd, wsd, wbsd);
  k_scan_sched<<<1, 64, 0, stream>>>(counts, offs, cursor, tblGU, tblDN, nact);
  k_assign<<<(T_TOK + 255) / 256, 256, 0, stream>>>(tki, cursor, pos, slot_tok);

  // --- merged gate/up GEMM with fused silu ---
  k_gemm8<0><<<GU_GRID, 512, 0, stream>>>(
      tblGU, nact, xb, nullptr, nullptr,
      wbg, wbu, wbd, wbsg, wbsu, wbsd,
      P1r, P1s, yr, out, offs, counts, slot_tok);

  // --- merged down GEMM (routed -> yr, shared -> out) ---
  k_gemm8<1><<<DN_GRID, 512, 0, stream>>>(
      tblDN, nact, xb, P1r, P1s,
      wbg, wbu, wbd, wbsg, wbsu, wbsd,
      P1r, P1s, yr, out, offs, counts, slot_tok);

  // --- combine routed into output ---
  k_combine<<<T_TOK, 256, 0, stream>>>(out, yr, tkw, pos);
}

// Round 16
// 502.202 us; speedup vs baseline: 1.1423x; 1.1423x over previous
//
#include <hip/hip_runtime.h>
#include <stdint.h>
#include <stdio.h>

#define T_TOK 4096
#define DMODEL 2048
#define NEXP 8
#define DFF 1408
#define DFFS 2816
#define NSLOT 8192   // T_TOK * 2

// schedule-table grid bounds (worst case): routed m-blocks sum <= 39
#define GU_GRID (16 * 22 + 39 * 11)   // 781
#define DN_GRID (16 * 8 + 39 * 8)     // 440
#define CONV_ALL 1536                 // all-weight convert blocks, interleaved 3:8
#define MIX_GRID (T_TOK + CONV_ALL)   // 5632 = 512 groups of 11 (3 conv + 8 router)

typedef unsigned short u16;
typedef short s16x8 __attribute__((ext_vector_type(8)));
typedef unsigned short u16x4 __attribute__((ext_vector_type(4)));
typedef __bf16 bf16x8 __attribute__((ext_vector_type(8)));
typedef float f32x4 __attribute__((ext_vector_type(4)));

__device__ __forceinline__ u16 f2bf(float f) {
  uint32_t u = __builtin_bit_cast(uint32_t, f);
  u += 0x7fffu + ((u >> 16) & 1u);
  return (u16)(u >> 16);
}
__device__ __forceinline__ float bf2f(u16 h) {
  uint32_t u = ((uint32_t)h) << 16;
  return __builtin_bit_cast(float, u);
}

// async global->LDS, 16B per lane; LDS dest = wave-uniform base + lane*16
__device__ __forceinline__ void gl16(const u16* g, u16* l) {
  __builtin_amdgcn_global_load_lds((const __attribute__((address_space(1))) void*)g,
                                   (__attribute__((address_space(3))) void*)l,
                                   16, 0, 0);
}

#define BARRIER() asm volatile("s_barrier" ::: "memory")
#define SBAR()    __builtin_amdgcn_sched_barrier(0)

__device__ __forceinline__ void conv8(const float* __restrict__ s, u16* __restrict__ d,
                                      long k) {
  float4 a = ((const float4*)s)[2 * k];
  float4 b = ((const float4*)s)[2 * k + 1];
  s16x8 r;
  r[0] = (short)f2bf(a.x); r[1] = (short)f2bf(a.y);
  r[2] = (short)f2bf(a.z); r[3] = (short)f2bf(a.w);
  r[4] = (short)f2bf(b.x); r[5] = (short)f2bf(b.y);
  r[6] = (short)f2bf(b.z); r[7] = (short)f2bf(b.w);
  ((s16x8*)d)[k] = r;
}

__global__ void k_zero(int* __restrict__ counts) {
  if (threadIdx.x < NEXP) counts[threadIdx.x] = 0;
}

// ---------------- router (1 tok/block, 4 waves, fused x->bf16) + INTERLEAVED converts --
// Grid = 512 groups of 11 blocks: in each group, r<3 -> convert block (ci = g*3+r),
// r>=3 -> router block (t = g*8+r-3). Interleaving puts convert (HBM-streaming) blocks
// on every CU from t=0, so they run at full BW UNDER the router's latency stalls --
// r14's appended layout phase-separated them (211us at 1.8TB/s; post-mortem lesson).
// Router math bitwise-identical to rounds 5-14.
__global__ void k_router(const float* __restrict__ x, const float* __restrict__ gw,
                         u16* __restrict__ xb,
                         float* __restrict__ tkw, int* __restrict__ tki,
                         int* __restrict__ counts,
                         const float* __restrict__ wgF, u16* __restrict__ wbg,
                         const float* __restrict__ wuF, u16* __restrict__ wbu,
                         const float* __restrict__ wsgF, u16* __restrict__ wbsg,
                         const float* __restrict__ wsuF, u16* __restrict__ wbsu,
                         const float* __restrict__ wdF, u16* __restrict__ wbd,
                         const float* __restrict__ wsdF, u16* __restrict__ wbsd) {
  const int g = blockIdx.x / 11;
  const int r = blockIdx.x % 11;
  if (r < 3) {   // ---- convert path (ci = g*3+r in [0, 1536)) ----
    const long ci = (long)g * 3 + r;
    const long N1 = (long)NEXP * DFF * DMODEL / 8;   // 2883584 (also wd size)
    const long NS = (long)DFFS * DMODEL / 8;         // 720896  (also wsd size)
    const long total = 3 * N1 + 3 * NS;
    const long stride = (long)CONV_ALL * 256;
    for (long i = ci * 256 + threadIdx.x; i < total; i += stride) {
      long k = i;
      if (k < N1)            conv8(wgF, wbg, k);
      else { k -= N1;
        if (k < N1)          conv8(wuF, wbu, k);
        else { k -= N1;
          if (k < NS)        conv8(wsgF, wbsg, k);
          else { k -= NS;
            if (k < NS)      conv8(wsuF, wbsu, k);
            else { k -= NS;
              if (k < N1)    conv8(wdF, wbd, k);
              else           conv8(wsdF, wbsd, k - N1);
            }
          }
        }
      }
    }
    return;
  }
  __shared__ double sm[NEXP];
  const int t = g * 8 + (r - 3);           // token in [0, 4096)
  int tid = threadIdx.x;
  int lane = tid & 63, wv = tid >> 6;      // 4 waves
  const float4* xr = (const float4*)(x + (size_t)t * DMODEL);
  const float4* gr = (const float4*)gw;
  int e0 = wv * 2, e1 = e0 + 1;
  double a0 = 0.0, a1 = 0.0;
#pragma unroll
  for (int it = 0; it < DMODEL / 4 / 64; ++it) {   // 8 iters
    int idx = it * 64 + lane;
    float4 xv = xr[idx];
    float4 g0 = gr[e0 * (DMODEL / 4) + idx];
    float4 g1 = gr[e1 * (DMODEL / 4) + idx];
    a0 += (double)xv.x * g0.x + (double)xv.y * g0.y +
          (double)xv.z * g0.z + (double)xv.w * g0.w;
    a1 += (double)xv.x * g1.x + (double)xv.y * g1.y +
          (double)xv.z * g1.z + (double)xv.w * g1.w;
    if (wv == 0) {   // fused x -> bf16 (wave 0 only)
      u16x4 rr = { f2bf(xv.x), f2bf(xv.y), f2bf(xv.z), f2bf(xv.w) };
      ((u16x4*)(xb + (size_t)t * DMODEL))[idx] = rr;
    }
  }
#pragma unroll
  for (int off = 32; off; off >>= 1) {
    a0 += __shfl_down(a0, off, 64);
    a1 += __shfl_down(a1, off, 64);
  }
  if (lane == 0) { sm[e0] = a0; sm[e1] = a1; }
  __syncthreads();
  if (tid == 0) {
    double acc[NEXP];
#pragma unroll
    for (int e = 0; e < NEXP; ++e) acc[e] = sm[e];
    int i0 = 0; double v0 = acc[0];
    for (int e = 1; e < NEXP; ++e) if (acc[e] > v0) { v0 = acc[e]; i0 = e; }
    int i1 = -1; double v1 = -1e300;
    for (int e = 0; e < NEXP; ++e) if (e != i0 && acc[e] > v1) { v1 = acc[e]; i1 = e; }
    double rr = exp(v1 - v0);
    float w0 = (float)(1.0 / (1.0 + rr));
    float w1 = 1.0f - w0;
    tkw[2 * t] = w0; tkw[2 * t + 1] = w1;
    tki[2 * t] = i0; tki[2 * t + 1] = i1;
    atomicAdd(&counts[i0], 1);
    atomicAdd(&counts[i1], 1);
  }
}

// ---------------- merged scan + schedule-table builder (round-9 ordering) ----------------
// desc: bit31 = shared flag, bits24-27 = expert, bits12-23 = mb, bits0-11 = nb.
// GU: nb indexes 128-col panels (g+u fused per block). DN: nb indexes 256-col.
// Shared entries FIRST (LPT for DOWN: shared-down blocks have 2x the K).
__global__ void k_scan_sched(const int* __restrict__ counts, int* __restrict__ offs,
                             int* __restrict__ cursor, int* __restrict__ tblGU,
                             int* __restrict__ tblDN, int* __restrict__ nact) {
  if (threadIdx.x != 0 || blockIdx.x != 0) return;
  int s = 0;
  for (int e = 0; e < NEXP; ++e) { offs[e] = s; cursor[e] = s; s += counts[e]; }
  offs[NEXP] = s;
  int g = 0, d = 0;
  for (int m = 0; m < T_TOK / 256; ++m) {
    for (int nb = 0; nb < DFFS / 128; ++nb)
      tblGU[g++] = (int)(0x80000000u | (m << 12) | nb);
    for (int nb = 0; nb < DMODEL / 256; ++nb)
      tblDN[d++] = (int)(0x80000000u | (m << 12) | nb);
  }
  for (int e = 0; e < NEXP; ++e) {
    int mb = (counts[e] + 255) >> 8;
    for (int m = 0; m < mb; ++m) {
      for (int nb = 0; nb < DFF / 128; ++nb)
        tblGU[g++] = (e << 24) | (m << 12) | nb;
      for (int nb = 0; nb < DMODEL / 256; ++nb)
        tblDN[d++] = (e << 24) | (m << 12) | nb;
    }
  }
  nact[0] = g; nact[1] = d;
}

__global__ void k_assign(const int* __restrict__ tki, int* __restrict__ cursor,
                         int* __restrict__ pos, int* __restrict__ slot_tok) {
  int t = blockIdx.x * 256 + threadIdx.x;
  if (t >= T_TOK) return;
#pragma unroll
  for (int k = 0; k < 2; ++k) {
    int e = tki[2 * t + k];
    int p = atomicAdd(&cursor[e], 1);
    pos[2 * t + k] = p;
    slot_tok[p] = t;
  }
}

// ---------------- 256-row NT bf16 GEMM, reads-lead pipeline (round-9), fused-silu GU --
// PHASE 0 = gate/up+silu fused: 256m x 128 cols, B-tile rows interleaved;
//   epilogue computes h = silu(g)*u in-register, writes h only.
// PHASE 1 = merged down (runtime K = 1408/2816), 256x256, writes yr / out.
// 512 thr = 8 waves (2M x 4N), BK=64, LDS 2 x 64KB dbuf, T2 XOR-swizzle.
template <int PHASE>
__launch_bounds__(512, 2)
__global__ void k_gemm8(const int* __restrict__ tbl, const int* __restrict__ nact,
                        const u16* __restrict__ xb,
                        const u16* __restrict__ hr, const u16* __restrict__ hs,
                        const u16* __restrict__ wbg, const u16* __restrict__ wbu,
                        const u16* __restrict__ wbd,
                        const u16* __restrict__ wbsg, const u16* __restrict__ wbsu,
                        const u16* __restrict__ wbsd,
                        u16* __restrict__ P1r, u16* __restrict__ P1s,
                        u16* __restrict__ yr, float* __restrict__ out,
                        const int* __restrict__ offs, const int* __restrict__ counts,
                        const int* __restrict__ slot_tok) {
  __shared__ __attribute__((aligned(16))) u16 lds[2 * 32768];  // 128 KiB

  if ((int)blockIdx.x >= nact[PHASE]) return;
  const int desc = tbl[blockIdx.x];
  const bool shrd = desc < 0;
  const int e = (desc >> 24) & 0xF;
  const int m0 = ((desc >> 12) & 0xFFF) * 256;
  const int n0 = (desc & 0xFFF) * (PHASE == 0 ? 128 : 256);

  const u16 *A, *Bg, *Bu;
  u16* C1;
  float* OF = nullptr;
  int base, cnt, HS, K;
  bool gather = false;
  if constexpr (PHASE == 0) {
    K = DMODEL;
    if (shrd) {
      A = xb; base = 0; cnt = T_TOK;
      Bg = wbsg; Bu = wbsu; C1 = P1s; HS = DFFS;
    } else {
      A = xb; gather = true; base = offs[e]; cnt = counts[e];
      size_t es = (size_t)e * DFF * DMODEL;
      Bg = wbg + es; Bu = wbu + es; C1 = P1r; HS = DFF;
    }
  } else {
    HS = DMODEL;
    if (shrd) {
      A = hs; base = 0; cnt = T_TOK; K = DFFS;
      Bg = Bu = wbsd; OF = out; C1 = nullptr;
    } else {
      A = hr; base = offs[e]; cnt = counts[e]; K = DFF;
      Bg = Bu = wbd + (size_t)e * DMODEL * DFF; C1 = yr;
    }
  }
  const int NT = K >> 6;

  int tid = threadIdx.x;
  int lane = tid & 63, wv = tid >> 6;
  int wm = wv >> 2, wn = wv & 3;
  int fr = lane & 15, fq = lane >> 4;

  // --- staging source pointers: 4 A-slabs + 4 B-slabs (64 rows each)
  int srow = tid >> 3;                     // wv*8 + (lane>>3), 0..63
  int sslot = (tid & 7) ^ (srow & 7);      // T2 pre-swizzle (involution)
  const u16* ap[4]; const u16* bp[4];
#pragma unroll
  for (int h = 0; h < 4; ++h) {
    int rr = h * 64 + srow;                // tile row 0..255
    int ra = m0 + rr; ra = ra < cnt ? ra : cnt - 1;
    int ga = gather ? slot_tok[base + ra] : base + ra;
    ap[h] = A + (size_t)ga * K + sslot * 8;
    const u16* bb;
    if constexpr (PHASE == 0) {
      // interleaved g/u B-tile: row rr -> wave wn_r = rr>>6, s = rr&63;
      // s<32: wg col n0+wn_r*32+s ; s>=32: wu col n0+wn_r*32+(s-32)
      int wnr = rr >> 6, s = rr & 63;
      int col = n0 + wnr * 32 + (s & 31);
      bb = (s < 32 ? Bg : Bu) + (size_t)col * K;
    } else {
      bb = Bg + (size_t)(n0 + rr) * K;
    }
    bp[h] = bb + sslot * 8;
  }

#define STG_A(h, bufi, kt) gl16(ap[h] + (size_t)(kt) * 64, \
                                lds + (bufi) * 32768 + (h) * 4096 + wv * 512)
#define STG_B(h, bufi, kt) gl16(bp[h] + (size_t)(kt) * 64, \
                                lds + (bufi) * 32768 + 16384 + (h) * 4096 + wv * 512)

  // --- read bases (u16 units); swizzled k-slot is lane-constant per ks
  int sKs0 = ((0 + fq) ^ (fr & 7)) * 8;
  int sKs1 = ((4 + fq) ^ (fr & 7)) * 8;
  int aBase = wm * 8192 + fr * 64;                                   // + i*1024
  int bBase = 16384 + (wn >> 1) * 8192 + ((wn & 1) * 64 + fr) * 64;  // + j*1024

  f32x4 acc[8][4];
#pragma unroll
  for (int i = 0; i < 8; ++i)
#pragma unroll
    for (int j = 0; j < 4; ++j) acc[i][j] = (f32x4){0.f, 0.f, 0.f, 0.f};

  // prologue: full tile0 + A-slabs of tile1
  STG_A(0, 0, 0); STG_A(1, 0, 0); STG_A(2, 0, 0); STG_A(3, 0, 0);
  STG_B(0, 0, 0); STG_B(1, 0, 0); STG_B(2, 0, 0); STG_B(3, 0, 0);
  if (NT > 1) { STG_A(0, 1, 1); STG_A(1, 1, 1); STG_A(2, 1, 1); STG_A(3, 1, 1); }
  if (NT > 1) asm volatile("s_waitcnt vmcnt(4)" ::: "memory");
  else        asm volatile("s_waitcnt vmcnt(0)" ::: "memory");
  BARRIER();
  SBAR();

  bf16x8 rAa[4][2], rAb[4][2], rB01[2][2], rB23[2][2];
#pragma unroll
  for (int il = 0; il < 4; ++il) {
    rAa[il][0] = *(const bf16x8*)(lds + aBase + il * 1024 + sKs0);
    rAa[il][1] = *(const bf16x8*)(lds + aBase + il * 1024 + sKs1);
  }
#pragma unroll
  for (int jl = 0; jl < 2; ++jl) {
    rB01[jl][0] = *(const bf16x8*)(lds + bBase + jl * 1024 + sKs0);
    rB01[jl][1] = *(const bf16x8*)(lds + bBase + jl * 1024 + sKs1);
  }

  for (int t = 0; t < NT; ++t) {
    const int buf = t & 1, nbuf = buf ^ 1;
    const u16* lbuf = lds + buf * 32768;
    const u16* lbufN = lds + nbuf * 32768;
    const bool hn1 = (t + 1) < NT, hn2 = (t + 2) < NT;

    // ---- s0: read B23(t); stage B0,B1(t+1)->nbuf; MFMA mq0 x nq0
#pragma unroll
    for (int jl = 0; jl < 2; ++jl) {
      rB23[jl][0] = *(const bf16x8*)(lbuf + bBase + (2 + jl) * 1024 + sKs0);
      rB23[jl][1] = *(const bf16x8*)(lbuf + bBase + (2 + jl) * 1024 + sKs1);
    }
    if (hn1) { STG_B(0, nbuf, t + 1); STG_B(1, nbuf, t + 1); }
    __builtin_amdgcn_s_setprio(1);
#pragma unroll
    for (int il = 0; il < 4; ++il)
#pragma unroll
      for (int jl = 0; jl < 2; ++jl) {
        acc[il][jl] = __builtin_amdgcn_mfma_f32_16x16x32_bf16(rAa[il][0], rB01[jl][0], acc[il][jl], 0, 0, 0);
        acc[il][jl] = __builtin_amdgcn_mfma_f32_16x16x32_bf16(rAa[il][1], rB01[jl][1], acc[il][jl], 0, 0, 0);
      }
    __builtin_amdgcn_s_setprio(0);

    // ---- s1: read A13(t); stage B2,B3(t+1)->nbuf; MFMA mq0 x nq1
#pragma unroll
    for (int il = 0; il < 4; ++il) {
      rAb[il][0] = *(const bf16x8*)(lbuf + aBase + (4 + il) * 1024 + sKs0);
      rAb[il][1] = *(const bf16x8*)(lbuf + aBase + (4 + il) * 1024 + sKs1);
    }
    if (hn1) { STG_B(2, nbuf, t + 1); STG_B(3, nbuf, t + 1); }
    __builtin_amdgcn_s_setprio(1);
#pragma unroll
    for (int il = 0; il < 4; ++il)
#pragma unroll
      for (int jl = 0; jl < 2; ++jl) {
        acc[il][2 + jl] = __builtin_amdgcn_mfma_f32_16x16x32_bf16(rAa[il][0], rB23[jl][0], acc[il][2 + jl], 0, 0, 0);
        acc[il][2 + jl] = __builtin_amdgcn_mfma_f32_16x16x32_bf16(rAa[il][1], rB23[jl][1], acc[il][2 + jl], 0, 0, 0);
      }
    __builtin_amdgcn_s_setprio(0);

    // ---- s2: drain reads + barrier (frees buf for t+2 A-stages); MFMA mq1 x nq0
    asm volatile("s_waitcnt lgkmcnt(0)" ::: "memory");
    BARRIER();
    SBAR();
    if (hn2) { STG_A(0, buf, t + 2); STG_A(1, buf, t + 2); }
    __builtin_amdgcn_s_setprio(1);
#pragma unroll
    for (int il = 0; il < 4; ++il)
#pragma unroll
      for (int jl = 0; jl < 2; ++jl) {
        acc[4 + il][jl] = __builtin_amdgcn_mfma_f32_16x16x32_bf16(rAb[il][0], rB01[jl][0], acc[4 + il][jl], 0, 0, 0);
        acc[4 + il][jl] = __builtin_amdgcn_mfma_f32_16x16x32_bf16(rAb[il][1], rB01[jl][1], acc[4 + il][jl], 0, 0, 0);
      }
    __builtin_amdgcn_s_setprio(0);

    // ---- s3: vmcnt+barrier (t+1 fully staged); stage A2,A3(t+2); read A02/B01(t+1); MFMA mq1 x nq1
    if (hn1) {
      if (hn2) asm volatile("s_waitcnt vmcnt(2)" ::: "memory");
      else     asm volatile("s_waitcnt vmcnt(0)" ::: "memory");
      BARRIER();
      SBAR();
      if (hn2) { STG_A(2, buf, t + 2); STG_A(3, buf, t + 2); }
#pragma unroll
      for (int il = 0; il < 4; ++il) {
        rAa[il][0] = *(const bf16x8*)(lbufN + aBase + il * 1024 + sKs0);
        rAa[il][1] = *(const bf16x8*)(lbufN + aBase + il * 1024 + sKs1);
      }
#pragma unroll
      for (int jl = 0; jl < 2; ++jl) {
        rB01[jl][0] = *(const bf16x8*)(lbufN + bBase + jl * 1024 + sKs0);
        rB01[jl][1] = *(const bf16x8*)(lbufN + bBase + jl * 1024 + sKs1);
      }
    }
    __builtin_amdgcn_s_setprio(1);
#pragma unroll
    for (int il = 0; il < 4; ++il)
#pragma unroll
      for (int jl = 0; jl < 2; ++jl) {
        acc[4 + il][2 + jl] = __builtin_amdgcn_mfma_f32_16x16x32_bf16(rAb[il][0], rB23[jl][0], acc[4 + il][2 + jl], 0, 0, 0);
        acc[4 + il][2 + jl] = __builtin_amdgcn_mfma_f32_16x16x32_bf16(rAb[il][1], rB23[jl][1], acc[4 + il][2 + jl], 0, 0, 0);
      }
    __builtin_amdgcn_s_setprio(0);
  }
#undef STG_A
#undef STG_B

  // --- epilogue ---
#pragma unroll
  for (int i = 0; i < 8; ++i) {
    int row_t = wm * 128 + i * 16 + fq * 4;
#pragma unroll
    for (int rr = 0; rr < 4; ++rr) {
      int m = m0 + row_t + rr;
      if (m >= cnt) continue;
      size_t rowoff = (size_t)(base + m) * (size_t)HS;
      if constexpr (PHASE == 0) {
        // h = silu(g) * u ; g = acc[i][jl], u = acc[i][2+jl], col = n0+wn*32+jl*16+fr
#pragma unroll
        for (int jl = 0; jl < 2; ++jl) {
          float gv = acc[i][jl][rr];
          float uv = acc[i][2 + jl][rr];
          float hval = (gv / (1.f + __expf(-gv))) * uv;
          C1[rowoff + (n0 + wn * 32 + jl * 16 + fr)] = f2bf(hval);
        }
      } else {
#pragma unroll
        for (int j = 0; j < 4; ++j) {
          int col_t = n0 + wn * 64 + j * 16 + fr;
          float v = acc[i][j][rr];
          if (shrd) OF[rowoff + col_t] = v;
          else      C1[rowoff + col_t] = f2bf(v);
        }
      }
    }
  }
}

// ---------------- y[t] += w0*yr[pos0] + w1*yr[pos1] ----------------
__global__ void k_combine(float* __restrict__ y, const u16* __restrict__ yr,
                          const float* __restrict__ tkw, const int* __restrict__ pos) {
  int t = blockIdx.x;
  int i = threadIdx.x;
  float w0 = tkw[2 * t], w1 = tkw[2 * t + 1];
  size_t p0 = (size_t)pos[2 * t] * DMODEL, p1 = (size_t)pos[2 * t + 1] * DMODEL;
  int d0 = i * 8;
  s16x8 a = *(const s16x8*)(yr + p0 + d0);
  s16x8 b = *(const s16x8*)(yr + p1 + d0);
  float* yo = y + (size_t)t * DMODEL + d0;
#pragma unroll
  for (int j = 0; j < 8; ++j)
    yo[j] += w0 * bf2f((u16)a[j]) + w1 * bf2f((u16)b[j]);
}

extern "C" void kernel_launch(void* const* d_in, const int* in_sizes, int n_in,
                              void* d_out, int out_size, void* d_ws, size_t ws_size,
                              hipStream_t stream) {
  const float* x   = (const float*)d_in[0];
  const float* gw  = (const float*)d_in[1];
  const float* wg  = (const float*)d_in[2];
  const float* wu  = (const float*)d_in[3];
  const float* wd  = (const float*)d_in[4];
  const float* wsg = (const float*)d_in[5];
  const float* wsu = (const float*)d_in[6];
  const float* wsd = (const float*)d_in[7];
  float* out = (float*)d_out;

  char* ws = (char*)d_ws;
  size_t o = 0;
  auto alloc = [&](size_t bytes) -> void* {
    void* p = ws + o;
    o += (bytes + 255) & ~(size_t)255;
    return p;
  };
  u16* xb   = (u16*)alloc((size_t)T_TOK * DMODEL * 2);
  u16* wbg  = (u16*)alloc((size_t)NEXP * DFF * DMODEL * 2);
  u16* wbu  = (u16*)alloc((size_t)NEXP * DFF * DMODEL * 2);
  u16* wbd  = (u16*)alloc((size_t)NEXP * DMODEL * DFF * 2);
  u16* wbsg = (u16*)alloc((size_t)DFFS * DMODEL * 2);
  u16* wbsu = (u16*)alloc((size_t)DFFS * DMODEL * 2);
  u16* wbsd = (u16*)alloc((size_t)DMODEL * DFFS * 2);
  u16* P1r  = (u16*)alloc((size_t)NSLOT * DFF * 2);    // h_r (silu fused in GU)
  u16* P1s  = (u16*)alloc((size_t)T_TOK * DFFS * 2);   // h_s
  u16* yr   = (u16*)alloc((size_t)NSLOT * DMODEL * 2);
  float* tkw = (float*)alloc((size_t)T_TOK * 2 * 4);
  int* tki   = (int*)alloc((size_t)T_TOK * 2 * 4);
  int* pos   = (int*)alloc((size_t)T_TOK * 2 * 4);
  int* slot_tok = (int*)alloc((size_t)NSLOT * 4);
  int* counts   = (int*)alloc(64);
  int* offs     = (int*)alloc(64);
  int* cursor   = (int*)alloc(64);
  int* tblGU    = (int*)alloc(GU_GRID * 4);
  int* tblDN    = (int*)alloc(DN_GRID * 4);
  int* nact     = (int*)alloc(64);
  if (o > ws_size) {
    fprintf(stderr, "kernel_launch: ws too small: need %zu have %zu\n", o, ws_size);
    return;
  }

  // --- routing (1 tok/block; ALL weight converts INTERLEAVED 3:8) ---
  k_zero<<<1, 64, 0, stream>>>(counts);
  k_router<<<MIX_GRID, 256, 0, stream>>>(x, gw, xb, tkw, tki, counts,
                                         wg, wbg, wu, wbu, wsg, wbsg, wsu, wbsu,
                                         wd, wbd, wsd, wbsd);
  k_scan_sched<<<1, 64, 0, stream>>>(counts, offs, cursor, tblGU, tblDN, nact);
  k_assign<<<(T_TOK + 255) / 256, 256, 0, stream>>>(tki, cursor, pos, slot_tok);

  // --- merged gate/up GEMM with fused silu ---
  k_gemm8<0><<<GU_GRID, 512, 0, stream>>>(
      tblGU, nact, xb, nullptr, nullptr,
      wbg, wbu, wbd, wbsg, wbsu, wbsd,
      P1r, P1s, yr, out, offs, counts, slot_tok);

  // --- merged down GEMM (routed -> yr, shared -> out) ---
  k_gemm8<1><<<DN_GRID, 512, 0, stream>>>(
      tblDN, nact, xb, P1r, P1s,
      wbg, wbu, wbd, wbsg, wbsu, wbsd,
      P1r, P1s, yr, out, offs, counts, slot_tok);

  // --- combine routed into output ---
  k_combine<<<T_TOK, 256, 0, stream>>>(out, yr, tkw, pos);
}

// Round 18
// 501.991 us; speedup vs baseline: 1.1427x; 1.0004x over previous
//
#include <hip/hip_runtime.h>
#include <stdint.h>
#include <stdio.h>

#define T_TOK 4096
#define DMODEL 2048
#define NEXP 8
#define DFF 1408
#define DFFS 2816
#define NSLOT 8192   // T_TOK * 2

// schedule-table grid bounds (worst case): routed m-blocks sum <= 39
#define GU_GRID (16 * 22 + 39 * 11)   // 781
#define DN_GRID (16 * 8 + 39 * 8)     // 440
#define CONV_ALL 1536                 // all-weight convert blocks, interleaved 3:8
#define MIX_GRID (T_TOK + CONV_ALL)   // 5632 = 512 groups of 11 (3 conv + 8 router)

typedef unsigned short u16;
typedef short s16x8 __attribute__((ext_vector_type(8)));
typedef unsigned short u16x4 __attribute__((ext_vector_type(4)));
typedef __bf16 bf16x8 __attribute__((ext_vector_type(8)));
typedef float f32x4 __attribute__((ext_vector_type(4)));

__device__ __forceinline__ u16 f2bf(float f) {
  uint32_t u = __builtin_bit_cast(uint32_t, f);
  u += 0x7fffu + ((u >> 16) & 1u);
  return (u16)(u >> 16);
}
__device__ __forceinline__ float bf2f(u16 h) {
  uint32_t u = ((uint32_t)h) << 16;
  return __builtin_bit_cast(float, u);
}

// async global->LDS, 16B per lane; LDS dest = wave-uniform base + lane*16
__device__ __forceinline__ void gl16(const u16* g, u16* l) {
  __builtin_amdgcn_global_load_lds((const __attribute__((address_space(1))) void*)g,
                                   (__attribute__((address_space(3))) void*)l,
                                   16, 0, 0);
}

#define BARRIER() asm volatile("s_barrier" ::: "memory")
#define SBAR()    __builtin_amdgcn_sched_barrier(0)

__device__ __forceinline__ void conv8(const float* __restrict__ s, u16* __restrict__ d,
                                      long k) {
  float4 a = ((const float4*)s)[2 * k];
  float4 b = ((const float4*)s)[2 * k + 1];
  s16x8 r;
  r[0] = (short)f2bf(a.x); r[1] = (short)f2bf(a.y);
  r[2] = (short)f2bf(a.z); r[3] = (short)f2bf(a.w);
  r[4] = (short)f2bf(b.x); r[5] = (short)f2bf(b.y);
  r[6] = (short)f2bf(b.z); r[7] = (short)f2bf(b.w);
  ((s16x8*)d)[k] = r;
}

__global__ void k_zero(int* __restrict__ counts) {
  if (threadIdx.x < NEXP) counts[threadIdx.x] = 0;
}

// ---------------- router (1 tok/block, 4 waves, fused x->bf16) + INTERLEAVED converts --
// Grid = 512 groups of 11 blocks: in each group, r<3 -> convert block (ci = g*3+r),
// r>=3 -> router block (t = g*8+r-3). Interleaving puts convert (HBM-streaming) blocks
// on every CU from t=0, so they run at full BW UNDER the router's latency stalls.
// Router math bitwise-identical to rounds 5-16.
__global__ void k_router(const float* __restrict__ x, const float* __restrict__ gw,
                         u16* __restrict__ xb,
                         float* __restrict__ tkw, int* __restrict__ tki,
                         int* __restrict__ counts,
                         const float* __restrict__ wgF, u16* __restrict__ wbg,
                         const float* __restrict__ wuF, u16* __restrict__ wbu,
                         const float* __restrict__ wsgF, u16* __restrict__ wbsg,
                         const float* __restrict__ wsuF, u16* __restrict__ wbsu,
                         const float* __restrict__ wdF, u16* __restrict__ wbd,
                         const float* __restrict__ wsdF, u16* __restrict__ wbsd) {
  const int g = blockIdx.x / 11;
  const int r = blockIdx.x % 11;
  if (r < 3) {   // ---- convert path (ci = g*3+r in [0, 1536)) ----
    const long ci = (long)g * 3 + r;
    const long N1 = (long)NEXP * DFF * DMODEL / 8;   // 2883584 (also wd size)
    const long NS = (long)DFFS * DMODEL / 8;         // 720896  (also wsd size)
    const long total = 3 * N1 + 3 * NS;
    const long stride = (long)CONV_ALL * 256;
    for (long i = ci * 256 + threadIdx.x; i < total; i += stride) {
      long k = i;
      if (k < N1)            conv8(wgF, wbg, k);
      else { k -= N1;
        if (k < N1)          conv8(wuF, wbu, k);
        else { k -= N1;
          if (k < NS)        conv8(wsgF, wbsg, k);
          else { k -= NS;
            if (k < NS)      conv8(wsuF, wbsu, k);
            else { k -= NS;
              if (k < N1)    conv8(wdF, wbd, k);
              else           conv8(wsdF, wbsd, k - N1);
            }
          }
        }
      }
    }
    return;
  }
  __shared__ double sm[NEXP];
  const int t = g * 8 + (r - 3);           // token in [0, 4096)
  int tid = threadIdx.x;
  int lane = tid & 63, wv = tid >> 6;      // 4 waves
  const float4* xr = (const float4*)(x + (size_t)t * DMODEL);
  const float4* gr = (const float4*)gw;
  int e0 = wv * 2, e1 = e0 + 1;
  double a0 = 0.0, a1 = 0.0;
#pragma unroll
  for (int it = 0; it < DMODEL / 4 / 64; ++it) {   // 8 iters
    int idx = it * 64 + lane;
    float4 xv = xr[idx];
    float4 g0 = gr[e0 * (DMODEL / 4) + idx];
    float4 g1 = gr[e1 * (DMODEL / 4) + idx];
    a0 += (double)xv.x * g0.x + (double)xv.y * g0.y +
          (double)xv.z * g0.z + (double)xv.w * g0.w;
    a1 += (double)xv.x * g1.x + (double)xv.y * g1.y +
          (double)xv.z * g1.z + (double)xv.w * g1.w;
    if (wv == 0) {   // fused x -> bf16 (wave 0 only)
      u16x4 rr = { f2bf(xv.x), f2bf(xv.y), f2bf(xv.z), f2bf(xv.w) };
      ((u16x4*)(xb + (size_t)t * DMODEL))[idx] = rr;
    }
  }
#pragma unroll
  for (int off = 32; off; off >>= 1) {
    a0 += __shfl_down(a0, off, 64);
    a1 += __shfl_down(a1, off, 64);
  }
  if (lane == 0) { sm[e0] = a0; sm[e1] = a1; }
  __syncthreads();
  if (tid == 0) {
    double acc[NEXP];
#pragma unroll
    for (int e = 0; e < NEXP; ++e) acc[e] = sm[e];
    int i0 = 0; double v0 = acc[0];
    for (int e = 1; e < NEXP; ++e) if (acc[e] > v0) { v0 = acc[e]; i0 = e; }
    int i1 = -1; double v1 = -1e300;
    for (int e = 0; e < NEXP; ++e) if (e != i0 && acc[e] > v1) { v1 = acc[e]; i1 = e; }
    double rr = exp(v1 - v0);
    float w0 = (float)(1.0 / (1.0 + rr));
    float w1 = 1.0f - w0;
    tkw[2 * t] = w0; tkw[2 * t + 1] = w1;
    tki[2 * t] = i0; tki[2 * t + 1] = i1;
    atomicAdd(&counts[i0], 1);
    atomicAdd(&counts[i1], 1);
  }
}

// ---------------- merged scan + schedule-table builder (round-9 ordering) ----------------
// desc: bit31 = shared flag, bits24-27 = expert, bits12-23 = mb, bits0-11 = nb.
// GU: nb indexes 128-col panels (g+u fused per block). DN: nb indexes 256-col.
// Shared entries FIRST (LPT for DOWN: shared-down blocks have 2x the K).
__global__ void k_scan_sched(const int* __restrict__ counts, int* __restrict__ offs,
                             int* __restrict__ cursor, int* __restrict__ tblGU,
                             int* __restrict__ tblDN, int* __restrict__ nact) {
  if (threadIdx.x != 0 || blockIdx.x != 0) return;
  int s = 0;
  for (int e = 0; e < NEXP; ++e) { offs[e] = s; cursor[e] = s; s += counts[e]; }
  offs[NEXP] = s;
  int g = 0, d = 0;
  for (int m = 0; m < T_TOK / 256; ++m) {
    for (int nb = 0; nb < DFFS / 128; ++nb)
      tblGU[g++] = (int)(0x80000000u | (m << 12) | nb);
    for (int nb = 0; nb < DMODEL / 256; ++nb)
      tblDN[d++] = (int)(0x80000000u | (m << 12) | nb);
  }
  for (int e = 0; e < NEXP; ++e) {
    int mb = (counts[e] + 255) >> 8;
    for (int m = 0; m < mb; ++m) {
      for (int nb = 0; nb < DFF / 128; ++nb)
        tblGU[g++] = (e << 24) | (m << 12) | nb;
      for (int nb = 0; nb < DMODEL / 256; ++nb)
        tblDN[d++] = (e << 24) | (m << 12) | nb;
    }
  }
  nact[0] = g; nact[1] = d;
}

__global__ void k_assign(const int* __restrict__ tki, int* __restrict__ cursor,
                         int* __restrict__ pos, int* __restrict__ slot_tok) {
  int t = blockIdx.x * 256 + threadIdx.x;
  if (t >= T_TOK) return;
#pragma unroll
  for (int k = 0; k < 2; ++k) {
    int e = tki[2 * t + k];
    int p = atomicAdd(&cursor[e], 1);
    pos[2 * t + k] = p;
    slot_tok[p] = t;
  }
}

// ---------------- 256-row NT bf16 GEMM, reads-lead pipeline (round-9), fused-silu GU --
// PHASE 0 = gate/up+silu fused: 256m x 128 cols, B-tile rows interleaved;
//   epilogue computes h = silu(g)*u in-register, writes h only.
// PHASE 1 = merged down (runtime K = 1408/2816), 256x256, writes yr / out.
// 512 thr = 8 waves (2M x 4N), BK=64, LDS 2 x 64KB dbuf, T2 XOR-swizzle.
template <int PHASE>
__launch_bounds__(512, 2)
__global__ void k_gemm8(const int* __restrict__ tbl, const int* __restrict__ nact,
                        const u16* __restrict__ xb,
                        const u16* __restrict__ hr, const u16* __restrict__ hs,
                        const u16* __restrict__ wbg, const u16* __restrict__ wbu,
                        const u16* __restrict__ wbd,
                        const u16* __restrict__ wbsg, const u16* __restrict__ wbsu,
                        const u16* __restrict__ wbsd,
                        u16* __restrict__ P1r, u16* __restrict__ P1s,
                        u16* __restrict__ yr, float* __restrict__ out,
                        const int* __restrict__ offs, const int* __restrict__ counts,
                        const int* __restrict__ slot_tok) {
  __shared__ __attribute__((aligned(16))) u16 lds[2 * 32768];  // 128 KiB

  if ((int)blockIdx.x >= nact[PHASE]) return;
  const int desc = tbl[blockIdx.x];
  const bool shrd = desc < 0;
  const int e = (desc >> 24) & 0xF;
  const int m0 = ((desc >> 12) & 0xFFF) * 256;
  const int n0 = (desc & 0xFFF) * (PHASE == 0 ? 128 : 256);

  const u16 *A, *Bg, *Bu;
  u16* C1;
  float* OF = nullptr;
  int base, cnt, HS, K;
  bool gather = false;
  if constexpr (PHASE == 0) {
    K = DMODEL;
    if (shrd) {
      A = xb; base = 0; cnt = T_TOK;
      Bg = wbsg; Bu = wbsu; C1 = P1s; HS = DFFS;
    } else {
      A = xb; gather = true; base = offs[e]; cnt = counts[e];
      size_t es = (size_t)e * DFF * DMODEL;
      Bg = wbg + es; Bu = wbu + es; C1 = P1r; HS = DFF;
    }
  } else {
    HS = DMODEL;
    if (shrd) {
      A = hs; base = 0; cnt = T_TOK; K = DFFS;
      Bg = Bu = wbsd; OF = out; C1 = nullptr;
    } else {
      A = hr; base = offs[e]; cnt = counts[e]; K = DFF;
      Bg = Bu = wbd + (size_t)e * DMODEL * DFF; C1 = yr;
    }
  }
  const int NT = K >> 6;

  int tid = threadIdx.x;
  int lane = tid & 63, wv = tid >> 6;
  int wm = wv >> 2, wn = wv & 3;
  int fr = lane & 15, fq = lane >> 4;

  // --- staging source pointers: 4 A-slabs + 4 B-slabs (64 rows each)
  int srow = tid >> 3;                     // wv*8 + (lane>>3), 0..63
  int sslot = (tid & 7) ^ (srow & 7);      // T2 pre-swizzle (involution)
  const u16* ap[4]; const u16* bp[4];
#pragma unroll
  for (int h = 0; h < 4; ++h) {
    int rr = h * 64 + srow;                // tile row 0..255
    int ra = m0 + rr; ra = ra < cnt ? ra : cnt - 1;
    int ga = gather ? slot_tok[base + ra] : base + ra;
    ap[h] = A + (size_t)ga * K + sslot * 8;
    const u16* bb;
    if constexpr (PHASE == 0) {
      // interleaved g/u B-tile: row rr -> wave wn_r = rr>>6, s = rr&63;
      // s<32: wg col n0+wn_r*32+s ; s>=32: wu col n0+wn_r*32+(s-32)
      int wnr = rr >> 6, s = rr & 63;
      int col = n0 + wnr * 32 + (s & 31);
      bb = (s < 32 ? Bg : Bu) + (size_t)col * K;
    } else {
      bb = Bg + (size_t)(n0 + rr) * K;
    }
    bp[h] = bb + sslot * 8;
  }

#define STG_A(h, bufi, kt) gl16(ap[h] + (size_t)(kt) * 64, \
                                lds + (bufi) * 32768 + (h) * 4096 + wv * 512)
#define STG_B(h, bufi, kt) gl16(bp[h] + (size_t)(kt) * 64, \
                                lds + (bufi) * 32768 + 16384 + (h) * 4096 + wv * 512)

  // --- read bases (u16 units); swizzled k-slot is lane-constant per ks
  int sKs0 = ((0 + fq) ^ (fr & 7)) * 8;
  int sKs1 = ((4 + fq) ^ (fr & 7)) * 8;
  int aBase = wm * 8192 + fr * 64;                                   // + i*1024
  int bBase = 16384 + (wn >> 1) * 8192 + ((wn & 1) * 64 + fr) * 64;  // + j*1024

  f32x4 acc[8][4];
#pragma unroll
  for (int i = 0; i < 8; ++i)
#pragma unroll
    for (int j = 0; j < 4; ++j) acc[i][j] = (f32x4){0.f, 0.f, 0.f, 0.f};

  // prologue: full tile0 + A-slabs of tile1
  STG_A(0, 0, 0); STG_A(1, 0, 0); STG_A(2, 0, 0); STG_A(3, 0, 0);
  STG_B(0, 0, 0); STG_B(1, 0, 0); STG_B(2, 0, 0); STG_B(3, 0, 0);
  if (NT > 1) { STG_A(0, 1, 1); STG_A(1, 1, 1); STG_A(2, 1, 1); STG_A(3, 1, 1); }
  if (NT > 1) asm volatile("s_waitcnt vmcnt(4)" ::: "memory");
  else        asm volatile("s_waitcnt vmcnt(0)" ::: "memory");
  BARRIER();
  SBAR();

  bf16x8 rAa[4][2], rAb[4][2], rB01[2][2], rB23[2][2];
#pragma unroll
  for (int il = 0; il < 4; ++il) {
    rAa[il][0] = *(const bf16x8*)(lds + aBase + il * 1024 + sKs0);
    rAa[il][1] = *(const bf16x8*)(lds + aBase + il * 1024 + sKs1);
  }
#pragma unroll
  for (int jl = 0; jl < 2; ++jl) {
    rB01[jl][0] = *(const bf16x8*)(lds + bBase + jl * 1024 + sKs0);
    rB01[jl][1] = *(const bf16x8*)(lds + bBase + jl * 1024 + sKs1);
  }

  for (int t = 0; t < NT; ++t) {
    const int buf = t & 1, nbuf = buf ^ 1;
    const u16* lbuf = lds + buf * 32768;
    const u16* lbufN = lds + nbuf * 32768;
    const bool hn1 = (t + 1) < NT, hn2 = (t + 2) < NT;

    // ---- s0: read B23(t); stage B0,B1(t+1)->nbuf; MFMA mq0 x nq0
#pragma unroll
    for (int jl = 0; jl < 2; ++jl) {
      rB23[jl][0] = *(const bf16x8*)(lbuf + bBase + (2 + jl) * 1024 + sKs0);
      rB23[jl][1] = *(const bf16x8*)(lbuf + bBase + (2 + jl) * 1024 + sKs1);
    }
    if (hn1) { STG_B(0, nbuf, t + 1); STG_B(1, nbuf, t + 1); }
    __builtin_amdgcn_s_setprio(1);
#pragma unroll
    for (int il = 0; il < 4; ++il)
#pragma unroll
      for (int jl = 0; jl < 2; ++jl) {
        acc[il][jl] = __builtin_amdgcn_mfma_f32_16x16x32_bf16(rAa[il][0], rB01[jl][0], acc[il][jl], 0, 0, 0);
        acc[il][jl] = __builtin_amdgcn_mfma_f32_16x16x32_bf16(rAa[il][1], rB01[jl][1], acc[il][jl], 0, 0, 0);
      }
    __builtin_amdgcn_s_setprio(0);

    // ---- s1: read A13(t); stage B2,B3(t+1)->nbuf; MFMA mq0 x nq1
#pragma unroll
    for (int il = 0; il < 4; ++il) {
      rAb[il][0] = *(const bf16x8*)(lbuf + aBase + (4 + il) * 1024 + sKs0);
      rAb[il][1] = *(const bf16x8*)(lbuf + aBase + (4 + il) * 1024 + sKs1);
    }
    if (hn1) { STG_B(2, nbuf, t + 1); STG_B(3, nbuf, t + 1); }
    __builtin_amdgcn_s_setprio(1);
#pragma unroll
    for (int il = 0; il < 4; ++il)
#pragma unroll
      for (int jl = 0; jl < 2; ++jl) {
        acc[il][2 + jl] = __builtin_amdgcn_mfma_f32_16x16x32_bf16(rAa[il][0], rB23[jl][0], acc[il][2 + jl], 0, 0, 0);
        acc[il][2 + jl] = __builtin_amdgcn_mfma_f32_16x16x32_bf16(rAa[il][1], rB23[jl][1], acc[il][2 + jl], 0, 0, 0);
      }
    __builtin_amdgcn_s_setprio(0);

    // ---- s2: drain reads + barrier (frees buf for t+2 A-stages); MFMA mq1 x nq0
    asm volatile("s_waitcnt lgkmcnt(0)" ::: "memory");
    BARRIER();
    SBAR();
    if (hn2) { STG_A(0, buf, t + 2); STG_A(1, buf, t + 2); }
    __builtin_amdgcn_s_setprio(1);
#pragma unroll
    for (int il = 0; il < 4; ++il)
#pragma unroll
      for (int jl = 0; jl < 2; ++jl) {
        acc[4 + il][jl] = __builtin_amdgcn_mfma_f32_16x16x32_bf16(rAb[il][0], rB01[jl][0], acc[4 + il][jl], 0, 0, 0);
        acc[4 + il][jl] = __builtin_amdgcn_mfma_f32_16x16x32_bf16(rAb[il][1], rB01[jl][1], acc[4 + il][jl], 0, 0, 0);
      }
    __builtin_amdgcn_s_setprio(0);

    // ---- s3: vmcnt+barrier (t+1 fully staged); stage A2,A3(t+2); read A02/B01(t+1); MFMA mq1 x nq1
    if (hn1) {
      if (hn2) asm volatile("s_waitcnt vmcnt(2)" ::: "memory");
      else     asm volatile("s_waitcnt vmcnt(0)" ::: "memory");
      BARRIER();
      SBAR();
      if (hn2) { STG_A(2, buf, t + 2); STG_A(3, buf, t + 2); }
#pragma unroll
      for (int il = 0; il < 4; ++il) {
        rAa[il][0] = *(const bf16x8*)(lbufN + aBase + il * 1024 + sKs0);
        rAa[il][1] = *(const bf16x8*)(lbufN + aBase + il * 1024 + sKs1);
      }
#pragma unroll
      for (int jl = 0; jl < 2; ++jl) {
        rB01[jl][0] = *(const bf16x8*)(lbufN + bBase + jl * 1024 + sKs0);
        rB01[jl][1] = *(const bf16x8*)(lbufN + bBase + jl * 1024 + sKs1);
      }
    }
    __builtin_amdgcn_s_setprio(1);
#pragma unroll
    for (int il = 0; il < 4; ++il)
#pragma unroll
      for (int jl = 0; jl < 2; ++jl) {
        acc[4 + il][2 + jl] = __builtin_amdgcn_mfma_f32_16x16x32_bf16(rAb[il][0], rB23[jl][0], acc[4 + il][2 + jl], 0, 0, 0);
        acc[4 + il][2 + jl] = __builtin_amdgcn_mfma_f32_16x16x32_bf16(rAb[il][1], rB23[jl][1], acc[4 + il][2 + jl], 0, 0, 0);
      }
    __builtin_amdgcn_s_setprio(0);
  }
#undef STG_A
#undef STG_B

  // --- epilogue ---
#pragma unroll
  for (int i = 0; i < 8; ++i) {
    int row_t = wm * 128 + i * 16 + fq * 4;
#pragma unroll
    for (int rr = 0; rr < 4; ++rr) {
      int m = m0 + row_t + rr;
      if (m >= cnt) continue;
      size_t rowoff = (size_t)(base + m) * (size_t)HS;
      if constexpr (PHASE == 0) {
        // h = silu(g) * u ; g = acc[i][jl], u = acc[i][2+jl], col = n0+wn*32+jl*16+fr
#pragma unroll
        for (int jl = 0; jl < 2; ++jl) {
          float gv = acc[i][jl][rr];
          float uv = acc[i][2 + jl][rr];
          float hval = (gv / (1.f + __expf(-gv))) * uv;
          C1[rowoff + (n0 + wn * 32 + jl * 16 + fr)] = f2bf(hval);
        }
      } else {
#pragma unroll
        for (int j = 0; j < 4; ++j) {
          int col_t = n0 + wn * 64 + j * 16 + fr;
          float v = acc[i][j][rr];
          if (shrd) OF[rowoff + col_t] = v;
          else      C1[rowoff + col_t] = f2bf(v);
        }
      }
    }
  }
}

// ---------------- y[t] += w0*yr[pos0] + w1*yr[pos1] ----------------
__global__ void k_combine(float* __restrict__ y, const u16* __restrict__ yr,
                          const float* __restrict__ tkw, const int* __restrict__ pos) {
  int t = blockIdx.x;
  int i = threadIdx.x;
  float w0 = tkw[2 * t], w1 = tkw[2 * t + 1];
  size_t p0 = (size_t)pos[2 * t] * DMODEL, p1 = (size_t)pos[2 * t + 1] * DMODEL;
  int d0 = i * 8;
  s16x8 a = *(const s16x8*)(yr + p0 + d0);
  s16x8 b = *(const s16x8*)(yr + p1 + d0);
  float* yo = y + (size_t)t * DMODEL + d0;
#pragma unroll
  for (int j = 0; j < 8; ++j)
    yo[j] += w0 * bf2f((u16)a[j]) + w1 * bf2f((u16)b[j]);
}

extern "C" void kernel_launch(void* const* d_in, const int* in_sizes, int n_in,
                              void* d_out, int out_size, void* d_ws, size_t ws_size,
                              hipStream_t stream) {
  const float* x   = (const float*)d_in[0];
  const float* gw  = (const float*)d_in[1];
  const float* wg  = (const float*)d_in[2];
  const float* wu  = (const float*)d_in[3];
  const float* wd  = (const float*)d_in[4];
  const float* wsg = (const float*)d_in[5];
  const float* wsu = (const float*)d_in[6];
  const float* wsd = (const float*)d_in[7];
  float* out = (float*)d_out;

  char* ws = (char*)d_ws;
  size_t o = 0;
  auto alloc = [&](size_t bytes) -> void* {
    void* p = ws + o;
    o += (bytes + 255) & ~(size_t)255;
    return p;
  };
  u16* xb   = (u16*)alloc((size_t)T_TOK * DMODEL * 2);
  u16* wbg  = (u16*)alloc((size_t)NEXP * DFF * DMODEL * 2);
  u16* wbu  = (u16*)alloc((size_t)NEXP * DFF * DMODEL * 2);
  u16* wbd  = (u16*)alloc((size_t)NEXP * DMODEL * DFF * 2);
  u16* wbsg = (u16*)alloc((size_t)DFFS * DMODEL * 2);
  u16* wbsu = (u16*)alloc((size_t)DFFS * DMODEL * 2);
  u16* wbsd = (u16*)alloc((size_t)DMODEL * DFFS * 2);
  u16* P1r  = (u16*)alloc((size_t)NSLOT * DFF * 2);    // h_r (silu fused in GU)
  u16* P1s  = (u16*)alloc((size_t)T_TOK * DFFS * 2);   // h_s
  u16* yr   = (u16*)alloc((size_t)NSLOT * DMODEL * 2);
  float* tkw = (float*)alloc((size_t)T_TOK * 2 * 4);
  int* tki   = (int*)alloc((size_t)T_TOK * 2 * 4);
  int* pos   = (int*)alloc((size_t)T_TOK * 2 * 4);
  int* slot_tok = (int*)alloc((size_t)NSLOT * 4);
  int* counts   = (int*)alloc(64);
  int* offs     = (int*)alloc(64);
  int* cursor   = (int*)alloc(64);
  int* tblGU    = (int*)alloc(GU_GRID * 4);
  int* tblDN    = (int*)alloc(DN_GRID * 4);
  int* nact     = (int*)alloc(64);
  if (o > ws_size) {
    fprintf(stderr, "kernel_launch: ws too small: need %zu have %zu\n", o, ws_size);
    return;
  }

  // --- routing (1 tok/block; ALL weight converts INTERLEAVED 3:8) ---
  k_zero<<<1, 64, 0, stream>>>(counts);
  k_router<<<MIX_GRID, 256, 0, stream>>>(x, gw, xb, tkw, tki, counts,
                                         wg, wbg, wu, wbu, wsg, wbsg, wsu, wbsu,
                                         wd, wbd, wsd, wbsd);
  k_scan_sched<<<1, 64, 0, stream>>>(counts, offs, cursor, tblGU, tblDN, nact);
  k_assign<<<(T_TOK + 255) / 256, 256, 0, stream>>>(tki, cursor, pos, slot_tok);

  // --- merged gate/up GEMM with fused silu ---
  k_gemm8<0><<<GU_GRID, 512, 0, stream>>>(
      tblGU, nact, xb, nullptr, nullptr,
      wbg, wbu, wbd, wbsg, wbsu, wbsd,
      P1r, P1s, yr, out, offs, counts, slot_tok);

  // --- merged down GEMM (routed -> yr, shared -> out) ---
  k_gemm8<1><<<DN_GRID, 512, 0, stream>>>(
      tblDN, nact, xb, P1r, P1s,
      wbg, wbu, wbd, wbsg, wbsu, wbsd,
      P1r, P1s, yr, out, offs, counts, slot_tok);

  // --- combine routed into output ---
  k_combine<<<T_TOK, 256, 0, stream>>>(out, yr, tkw, pos);
}